// Round 5
// baseline (916.571 us; speedup 1.0000x reference)
//
#include <hip/hip_runtime.h>
#include <cstdint>

#define H 128
#define NNODES 20000
#define NEDGES 640000
#define TILE 64
#define SCAN_BLOCKS 20

typedef unsigned short ushort_t;
typedef __attribute__((ext_vector_type(8))) short short8;
typedef __attribute__((ext_vector_type(4))) float floatx4;

__device__ __forceinline__ ushort_t f2bf(float f){
  uint32_t u = __builtin_bit_cast(uint32_t, f);
  u += 0x7fffu + ((u >> 16) & 1u);           // RNE
  return (ushort_t)(u >> 16);
}
__device__ __forceinline__ float bf2f(ushort_t s){
  uint32_t u = ((uint32_t)s) << 16;
  return __builtin_bit_cast(float, u);
}
// fast silu: v_exp_f32 + v_rcp_f32
__device__ __forceinline__ float silu_f(float x){
  float e = __builtin_amdgcn_exp2f(-1.44269504089f * x);
  return x * __builtin_amdgcn_rcpf(1.f + e);
}
__device__ __forceinline__ void lds_fence(){
  asm volatile("s_waitcnt lgkmcnt(0)" ::: "memory");
}

// ---- setup: weight transpose+cvt, h cvt, degree histogram, zero m_i/pos_sum
__global__ void setup_kernel(const float* __restrict__ eW1, const float* __restrict__ eW2,
                             const float* __restrict__ cW1, const float* __restrict__ nW1,
                             const float* __restrict__ nW2, const float* __restrict__ h,
                             const int* __restrict__ ei,
                             ushort_t* __restrict__ eW1t, ushort_t* __restrict__ eW2t,
                             ushort_t* __restrict__ cW1t, ushort_t* __restrict__ nW1t,
                             ushort_t* __restrict__ nW2t, ushort_t* __restrict__ hb,
                             int* __restrict__ hist, float4* __restrict__ zbase){
  int idx = blockIdx.x * 256 + threadIdx.x;
  if (idx < 32768){                      // eW1t[n*256+k] = eW1[k*128+n], k<256
    int n = idx >> 8, k = idx & 255;
    eW1t[idx] = f2bf(eW1[k * H + n]);
  } else if (idx < 49152){
    int j = idx - 32768; int n = j >> 7, k = j & 127;
    eW2t[j] = f2bf(eW2[k * H + n]);
  } else if (idx < 65536){
    int j = idx - 49152; int n = j >> 7, k = j & 127;
    cW1t[j] = f2bf(cW1[k * H + n]);
  } else if (idx < 98304){
    int j = idx - 65536; int n = j >> 8, k = j & 255;
    nW1t[j] = f2bf(nW1[k * H + n]);
  } else if (idx < 114688){
    int j = idx - 98304; int n = j >> 7, k = j & 127;
    nW2t[j] = f2bf(nW2[k * H + n]);
  } else if (idx < 434688){              // h fp32 -> bf16, 8 elems/thread
    int k = idx - 114688;
    const float4* p = (const float4*)(h + (size_t)k * 8);
    float4 v0 = p[0], v1 = p[1];
    ushort_t tmp[8];
    tmp[0]=f2bf(v0.x); tmp[1]=f2bf(v0.y); tmp[2]=f2bf(v0.z); tmp[3]=f2bf(v0.w);
    tmp[4]=f2bf(v1.x); tmp[5]=f2bf(v1.y); tmp[6]=f2bf(v1.z); tmp[7]=f2bf(v1.w);
    *(short8*)(hb + (size_t)k * 8) = *(const short8*)tmp;
  } else if (idx < 1074688){             // degree histogram
    int j = idx - 434688;
    atomicAdd(&hist[ei[j]], 1);
  } else {                               // zero m_i + pos_sum (655000 float4s)
    int j = idx - 1074688;
    if (j < 655000) zbase[j] = make_float4(0.f, 0.f, 0.f, 0.f);
  }
}

// ---------------- CSR build ------------------------------------------------
__global__ void scanA_kernel(const int* __restrict__ hist, int* __restrict__ head,
                             int* __restrict__ totals){
  __shared__ int s[1024];
  const int t = threadIdx.x;
  const int idx = blockIdx.x * 1024 + t;
  int v = (idx < NNODES) ? hist[idx] : 0;
  s[t] = v;
  __syncthreads();
  for (int off = 1; off < 1024; off <<= 1){
    int tmp = (t >= off) ? s[t - off] : 0;
    __syncthreads();
    s[t] += tmp;
    __syncthreads();
  }
  if (idx < NNODES) head[idx] = s[t] - v;          // exclusive within block
  if (t == 1023) totals[blockIdx.x] = s[t];
}

__global__ void scanC_kernel(const int* __restrict__ totals, int* __restrict__ head){
  __shared__ int off_s;
  if (threadIdx.x == 0){
    int a = 0;
    for (int i = 0; i < (int)blockIdx.x; i++) a += totals[i];
    off_s = a;
  }
  __syncthreads();
  int idx = blockIdx.x * 1024 + threadIdx.x;
  if (idx < NNODES) head[idx] += off_s;
}

__global__ void scatter_kernel(const int* __restrict__ ei, int* __restrict__ head,
                               int2* __restrict__ spair){
  int idx = blockIdx.x * 256 + threadIdx.x;
  if (idx < NEDGES){
    int r = ei[idx], c = ei[NEDGES + idx];
    int p = atomicAdd(&head[r], 1);
    spair[p] = make_int2(r, c);
  }
}

// ---------------- edge kernel ----------------------------------------------
// BARRIER-FREE: each wave owns 16 edges end-to-end (m=16, n=128 full width).
// t1/m_ij transposes go through a private per-wave LDS slice; intra-wave
// ordering only needs lgkmcnt(0). Per-edge weight via in-wave shfl reduce.
__global__ __launch_bounds__(256, 4) void edge_kernel(
    const ushort_t* __restrict__ hb, const float* __restrict__ pos,
    const int2* __restrict__ spair,
    const float* __restrict__ eW1, const float* __restrict__ eb1,
    const float* __restrict__ eb2, const float* __restrict__ cb1,
    const float* __restrict__ cW2,
    const ushort_t* __restrict__ eW1t, const ushort_t* __restrict__ eW2t,
    const ushort_t* __restrict__ cW1t,
    float* __restrict__ m_i, float* __restrict__ pos_sum)
{
  __shared__ __align__(16) ushort_t tbuf[4][16 * 136];
  __shared__ float wbuf[4][16];

  const int t = threadIdx.x;
  const int w = t >> 6;
  const int lane = t & 63, q = lane >> 4, ln = lane & 15;
  const int wb = blockIdx.x * TILE + w * 16;   // this wave's 16 edges
  ushort_t* tb = tbuf[w];

  // every lane mirrors edge (ln): geometry fully in registers
  int2 rc = spair[wb + ln];
  float ax = pos[rc.x*3+0] - pos[rc.y*3+0];
  float ay = pos[rc.x*3+1] - pos[rc.y*3+1];
  float az = pos[rc.x*3+2] - pos[rc.y*3+2];
  float sq = ax*ax + ay*ay + az*az;

  // ---- GEMM1: [16 x 256] @ eW1t -> [16 x 128], A direct from global bf16
  floatx4 acc[8];
  #pragma unroll
  for (int nt = 0; nt < 8; nt++) acc[nt] = (floatx4)0.f;
  #pragma unroll
  for (int ks = 0; ks < 8; ks++){
    const int sl = (ks & 3) * 32 + q * 8;
    int src = (ks < 4) ? rc.x : rc.y;
    short8 a = *(const short8*)(hb + (size_t)src * H + sl);
    #pragma unroll
    for (int nt = 0; nt < 8; nt++){
      short8 b = *(const short8*)(eW1t + (size_t)(nt*16 + ln) * 256 + ks*32 + q*8);
      acc[nt] = __builtin_amdgcn_mfma_f32_16x16x32_bf16(a, b, acc[nt], 0, 0, 0);
    }
  }
  // epi1: + sq*w256 + eb1, silu, write t1 to LDS (A-layout transpose)
  {
    float sqr[4];
    #pragma unroll
    for (int r = 0; r < 4; r++) sqr[r] = __shfl(sq, q*4 + r, 16);
    #pragma unroll
    for (int nt = 0; nt < 8; nt++){
      int n = nt*16 + ln;
      float w256 = eW1[256 * H + n];
      float e1   = eb1[n];
      #pragma unroll
      for (int r = 0; r < 4; r++){
        float x = acc[nt][r] + sqr[r] * w256 + e1;
        tb[(q*4 + r) * 136 + n] = f2bf(silu_f(x));
      }
    }
  }
  lds_fence();

  // ---- GEMM2: t1 @ eW2t -> m_ij
  floatx4 acc2[8];
  #pragma unroll
  for (int nt = 0; nt < 8; nt++) acc2[nt] = (floatx4)0.f;
  #pragma unroll
  for (int ks = 0; ks < 4; ks++){
    short8 a = *(const short8*)(tb + ln * 136 + ks*32 + q*8);
    #pragma unroll
    for (int nt = 0; nt < 8; nt++){
      short8 b = *(const short8*)(eW2t + (size_t)(nt*16 + ln) * 128 + ks*32 + q*8);
      acc2[nt] = __builtin_amdgcn_mfma_f32_16x16x32_bf16(a, b, acc2[nt], 0, 0, 0);
    }
  }
  lds_fence();                                     // t1 reads done before overwrite
  // epi2: silu(acc2 + eb2) -> m_ij, overwrite LDS slice
  {
    #pragma unroll
    for (int nt = 0; nt < 8; nt++){
      int n = nt*16 + ln;
      float e2 = eb2[n];
      #pragma unroll
      for (int r = 0; r < 4; r++){
        float mv = silu_f(acc2[nt][r] + e2);
        tb[(q*4 + r) * 136 + n] = f2bf(mv);
      }
    }
  }
  lds_fence();

  // ---- GEMM3: m_ij @ cW1t ; dot with cW2 -> per-edge scalar weight
  floatx4 acc3[8];
  #pragma unroll
  for (int nt = 0; nt < 8; nt++) acc3[nt] = (floatx4)0.f;
  #pragma unroll
  for (int ks = 0; ks < 4; ks++){
    short8 a = *(const short8*)(tb + ln * 136 + ks*32 + q*8);
    #pragma unroll
    for (int nt = 0; nt < 8; nt++){
      short8 b = *(const short8*)(cW1t + (size_t)(nt*16 + ln) * 128 + ks*32 + q*8);
      acc3[nt] = __builtin_amdgcn_mfma_f32_16x16x32_bf16(a, b, acc3[nt], 0, 0, 0);
    }
  }
  {
    float pr[4] = {0.f, 0.f, 0.f, 0.f};
    #pragma unroll
    for (int nt = 0; nt < 8; nt++){
      int n = nt*16 + ln;
      float c1 = cb1[n], c2v = cW2[n];
      #pragma unroll
      for (int r = 0; r < 4; r++)
        pr[r] += silu_f(acc3[nt][r] + c1) * c2v;
    }
    #pragma unroll
    for (int r = 0; r < 4; r++){
      pr[r] += __shfl_xor(pr[r], 1, 16);
      pr[r] += __shfl_xor(pr[r], 2, 16);
      pr[r] += __shfl_xor(pr[r], 4, 16);
      pr[r] += __shfl_xor(pr[r], 8, 16);
    }
    if (ln == 0){
      #pragma unroll
      for (int r = 0; r < 4; r++) wbuf[w][q*4 + r] = pr[r];
    }
  }
  lds_fence();

  // ---- m_i segmented reduce: 64 lanes x 2 cols, 16 edges (rows sorted)
  {
    int c2 = lane * 2;
    float a0 = 0.f, a1 = 0.f;
    int cur = __shfl(rc.x, 0, 16);
    #pragma unroll 4
    for (int mm = 0; mm < 16; mm++){
      int rr = __shfl(rc.x, mm, 16);
      uint32_t v = *(const uint32_t*)(tb + mm * 136 + c2);
      if (rr != cur){
        unsafeAtomicAdd(&m_i[(size_t)cur * H + c2],     a0);
        unsafeAtomicAdd(&m_i[(size_t)cur * H + c2 + 1], a1);
        a0 = 0.f; a1 = 0.f; cur = rr;
      }
      a0 += bf2f((ushort_t)(v & 0xffffu));
      a1 += bf2f((ushort_t)(v >> 16));
    }
    unsafeAtomicAdd(&m_i[(size_t)cur * H + c2],     a0);
    unsafeAtomicAdd(&m_i[(size_t)cur * H + c2 + 1], a1);
  }
  // ---- pos scatter: lane (q,ln) handles coord q of edge ln (q<3)
  if (q < 3){
    float val = (q == 0) ? ax : (q == 1) ? ay : az;
    float s = __builtin_amdgcn_rsqf(sq + 1e-8f) * wbuf[w][ln];
    unsafeAtomicAdd(&pos_sum[rc.x * 3 + q], val * s);
  }
}

// ---------------- node kernel (barrier-free, per-wave 16 nodes) -------------
__global__ __launch_bounds__(256, 4) void node_kernel(
    const float* __restrict__ h, const ushort_t* __restrict__ hb,
    const float* __restrict__ pos,
    const float* __restrict__ nb1, const float* __restrict__ nb2,
    const ushort_t* __restrict__ nW1t, const ushort_t* __restrict__ nW2t,
    const float* __restrict__ m_i, const float* __restrict__ pos_sum,
    const int* __restrict__ hist,
    float* __restrict__ h_out, float* __restrict__ pos_out)
{
  __shared__ __align__(16) ushort_t tbuf[4][16 * 136];
  const int t = threadIdx.x;
  const int w = t >> 6;
  const int lane = t & 63, q = lane >> 4, ln = lane & 15;
  const int wb = blockIdx.x * 64 + w * 16;
  ushort_t* tb = tbuf[w];

  const int node_l = wb + ln;
  const int ncl = (node_l < NNODES) ? node_l : (NNODES - 1);

  if (q == 0 && node_l < NNODES){
    float c = fmaxf((float)hist[node_l], 1.f);
    float invc = __builtin_amdgcn_rcpf(c);
    pos_out[node_l*3+0] = pos[node_l*3+0] + pos_sum[node_l*3+0] * invc;
    pos_out[node_l*3+1] = pos[node_l*3+1] + pos_sum[node_l*3+1] * invc;
    pos_out[node_l*3+2] = pos[node_l*3+2] + pos_sum[node_l*3+2] * invc;
  }

  // ---- GEMM1: [16 x 256] ([h | m_i]) @ nW1t
  floatx4 acc[8];
  #pragma unroll
  for (int nt = 0; nt < 8; nt++) acc[nt] = (floatx4)0.f;
  #pragma unroll
  for (int ks = 0; ks < 8; ks++){
    short8 a;
    if (ks < 4){
      a = *(const short8*)(hb + (size_t)ncl * H + ks*32 + q*8);
    } else {
      const float* mp = m_i + (size_t)ncl * H + (ks - 4)*32 + q*8;
      float4 v0 = *(const float4*)mp;
      float4 v1 = *(const float4*)(mp + 4);
      ushort_t tmp[8];
      tmp[0]=f2bf(v0.x); tmp[1]=f2bf(v0.y); tmp[2]=f2bf(v0.z); tmp[3]=f2bf(v0.w);
      tmp[4]=f2bf(v1.x); tmp[5]=f2bf(v1.y); tmp[6]=f2bf(v1.z); tmp[7]=f2bf(v1.w);
      a = *(const short8*)tmp;
    }
    #pragma unroll
    for (int nt = 0; nt < 8; nt++){
      short8 b = *(const short8*)(nW1t + (size_t)(nt*16 + ln) * 256 + ks*32 + q*8);
      acc[nt] = __builtin_amdgcn_mfma_f32_16x16x32_bf16(a, b, acc[nt], 0, 0, 0);
    }
  }
  {
    #pragma unroll
    for (int nt = 0; nt < 8; nt++){
      int n = nt*16 + ln;
      float b1 = nb1[n];
      #pragma unroll
      for (int r = 0; r < 4; r++)
        tb[(q*4 + r) * 136 + n] = f2bf(silu_f(acc[nt][r] + b1));
    }
  }
  lds_fence();

  // ---- GEMM2: t1 @ nW2t ; residual write
  floatx4 acc2[8];
  #pragma unroll
  for (int nt = 0; nt < 8; nt++) acc2[nt] = (floatx4)0.f;
  #pragma unroll
  for (int ks = 0; ks < 4; ks++){
    short8 a = *(const short8*)(tb + ln * 136 + ks*32 + q*8);
    #pragma unroll
    for (int nt = 0; nt < 8; nt++){
      short8 b = *(const short8*)(nW2t + (size_t)(nt*16 + ln) * 128 + ks*32 + q*8);
      acc2[nt] = __builtin_amdgcn_mfma_f32_16x16x32_bf16(a, b, acc2[nt], 0, 0, 0);
    }
  }
  {
    #pragma unroll
    for (int nt = 0; nt < 8; nt++){
      int n = nt*16 + ln;
      float b2 = nb2[n];
      #pragma unroll
      for (int r = 0; r < 4; r++){
        int node = wb + q*4 + r;
        if (node < NNODES)
          h_out[(size_t)node * H + n] = h[(size_t)node * H + n] + acc2[nt][r] + b2;
      }
    }
  }
}

// ---------------- launch ----------------------------------------------------
extern "C" void kernel_launch(void* const* d_in, const int* in_sizes, int n_in,
                              void* d_out, int out_size, void* d_ws, size_t ws_size,
                              hipStream_t stream){
  const float* h   = (const float*)d_in[0];
  const float* pos = (const float*)d_in[1];
  const int*   ei  = (const int*)d_in[2];
  const float* eW1 = (const float*)d_in[3];
  const float* eb1 = (const float*)d_in[4];
  const float* eW2 = (const float*)d_in[5];
  const float* eb2 = (const float*)d_in[6];
  const float* cW1 = (const float*)d_in[7];
  const float* cb1 = (const float*)d_in[8];
  const float* cW2 = (const float*)d_in[9];
  const float* nW1 = (const float*)d_in[10];
  const float* nb1 = (const float*)d_in[11];
  const float* nW2 = (const float*)d_in[12];
  const float* nb2 = (const float*)d_in[13];

  char* ws = (char*)d_ws;
  float*    m_i     = (float*)   (ws);                 // 10,240,000 B
  float*    pos_sum = (float*)   (ws + 10240000);      //    240,000 B
  int*      hist    = (int*)     (ws + 10480000);      //     80,000 B
  int*      head    = (int*)     (ws + 10560000);      //     80,000 B
  int*      totals  = (int*)     (ws + 10640000);      //      2,048 B
  int2*     spair   = (int2*)    (ws + 10644096);      //  5,120,000 B
  ushort_t* h_bf    = (ushort_t*)(ws + 15764096);      //  5,120,000 B
  ushort_t* eW1t    = (ushort_t*)(ws + 20884096);      //     65,536 B
  ushort_t* eW2t    = (ushort_t*)(ws + 20949632);      //     32,768 B
  ushort_t* cW1t    = (ushort_t*)(ws + 20982400);      //     32,768 B
  ushort_t* nW1t    = (ushort_t*)(ws + 21015168);      //     65,536 B
  ushort_t* nW2t    = (ushort_t*)(ws + 21080704);      //     32,768 B

  hipMemsetAsync(hist, 0, 80000, stream);              // hist only; m_i/pos_sum zeroed in setup

  setup_kernel<<<6757, 256, 0, stream>>>(eW1, eW2, cW1, nW1, nW2, h, ei,
                                         eW1t, eW2t, cW1t, nW1t, nW2t, h_bf, hist,
                                         (float4*)ws);
  scanA_kernel<<<SCAN_BLOCKS, 1024, 0, stream>>>(hist, head, totals);
  scanC_kernel<<<SCAN_BLOCKS, 1024, 0, stream>>>(totals, head);
  scatter_kernel<<<(NEDGES + 255) / 256, 256, 0, stream>>>(ei, head, spair);

  edge_kernel<<<NEDGES / TILE, 256, 0, stream>>>(h_bf, pos, spair,
                                                 eW1, eb1, eb2, cb1, cW2,
                                                 eW1t, eW2t, cW1t, m_i, pos_sum);

  float* h_out   = (float*)d_out;
  float* pos_out = h_out + (size_t)NNODES * H;
  node_kernel<<<(NNODES + 63) / 64, 256, 0, stream>>>(h, h_bf, pos, nb1, nb2,
                                                      nW1t, nW2t, m_i, pos_sum,
                                                      hist, h_out, pos_out);
}

// Round 7
// 457.251 us; speedup vs baseline: 2.0045x; 2.0045x over previous
//
#include <hip/hip_runtime.h>
#include <hip/hip_bf16.h>
#include <cstdint>

#define H 128
#define NNODES 20000
#define NEDGES 640000
#define TILE 64
#define SCAN_BLOCKS 20

typedef unsigned short ushort_t;
typedef __attribute__((ext_vector_type(8))) short short8;
typedef __attribute__((ext_vector_type(4))) float floatx4;

__device__ __forceinline__ ushort_t f2bf(float f){
  uint32_t u = __builtin_bit_cast(uint32_t, f);
  u += 0x7fffu + ((u >> 16) & 1u);           // RNE
  return (ushort_t)(u >> 16);
}
__device__ __forceinline__ float bf2f(ushort_t s){
  uint32_t u = ((uint32_t)s) << 16;
  return __builtin_bit_cast(float, u);
}
// packed RNE fp32x2 -> bf16x2 (v_cvt_pk_bf16_f32 on gfx950)
__device__ __forceinline__ uint32_t pk2bf(float lo, float hi){
  __hip_bfloat162 h2 = __float22bfloat162_rn(make_float2(lo, hi));
  uint32_t u;
  __builtin_memcpy(&u, &h2, 4);
  return u;
}
// fast silu: v_exp_f32 + v_rcp_f32
__device__ __forceinline__ float silu_f(float x){
  float e = __builtin_amdgcn_exp2f(-1.44269504089f * x);
  return x * __builtin_amdgcn_rcpf(1.f + e);
}

// ---- setup: weight transpose+cvt, h cvt, degree histogram, zero m_i/pos_sum
__global__ void setup_kernel(const float* __restrict__ eW1, const float* __restrict__ eW2,
                             const float* __restrict__ cW1, const float* __restrict__ nW1,
                             const float* __restrict__ nW2, const float* __restrict__ h,
                             const int* __restrict__ ei,
                             ushort_t* __restrict__ eW1t, ushort_t* __restrict__ eW2t,
                             ushort_t* __restrict__ cW1t, ushort_t* __restrict__ nW1t,
                             ushort_t* __restrict__ nW2t, ushort_t* __restrict__ hb,
                             int* __restrict__ hist, float4* __restrict__ zbase){
  int idx = blockIdx.x * 256 + threadIdx.x;
  if (idx < 32768){                      // eW1t[n*256+k] = eW1[k*128+n], k<256
    int n = idx >> 8, k = idx & 255;
    eW1t[idx] = f2bf(eW1[k * H + n]);
  } else if (idx < 49152){
    int j = idx - 32768; int n = j >> 7, k = j & 127;
    eW2t[j] = f2bf(eW2[k * H + n]);
  } else if (idx < 65536){
    int j = idx - 49152; int n = j >> 7, k = j & 127;
    cW1t[j] = f2bf(cW1[k * H + n]);
  } else if (idx < 98304){
    int j = idx - 65536; int n = j >> 8, k = j & 255;
    nW1t[j] = f2bf(nW1[k * H + n]);
  } else if (idx < 114688){
    int j = idx - 98304; int n = j >> 7, k = j & 127;
    nW2t[j] = f2bf(nW2[k * H + n]);
  } else if (idx < 434688){              // h fp32 -> bf16, 8 elems/thread, packed cvt
    int k = idx - 114688;
    const float4* p = (const float4*)(h + (size_t)k * 8);
    float4 v0 = p[0], v1 = p[1];
    uint4 uu;
    uu.x = pk2bf(v0.x, v0.y); uu.y = pk2bf(v0.z, v0.w);
    uu.z = pk2bf(v1.x, v1.y); uu.w = pk2bf(v1.z, v1.w);
    *(uint4*)(hb + (size_t)k * 8) = uu;
  } else if (idx < 1074688){             // degree histogram
    int j = idx - 434688;
    atomicAdd(&hist[ei[j]], 1);
  } else {                               // zero m_i + pos_sum (655000 float4s)
    int j = idx - 1074688;
    if (j < 655000) zbase[j] = make_float4(0.f, 0.f, 0.f, 0.f);
  }
}

// ---------------- CSR build ------------------------------------------------
__global__ void scanA_kernel(const int* __restrict__ hist, int* __restrict__ head,
                             int* __restrict__ totals){
  __shared__ int s[1024];
  const int t = threadIdx.x;
  const int idx = blockIdx.x * 1024 + t;
  int v = (idx < NNODES) ? hist[idx] : 0;
  s[t] = v;
  __syncthreads();
  for (int off = 1; off < 1024; off <<= 1){
    int tmp = (t >= off) ? s[t - off] : 0;
    __syncthreads();
    s[t] += tmp;
    __syncthreads();
  }
  if (idx < NNODES) head[idx] = s[t] - v;          // exclusive within block
  if (t == 1023) totals[blockIdx.x] = s[t];
}

__global__ void scanC_kernel(const int* __restrict__ totals, int* __restrict__ head){
  __shared__ int off_s;
  if (threadIdx.x == 0){
    int a = 0;
    for (int i = 0; i < (int)blockIdx.x; i++) a += totals[i];
    off_s = a;
  }
  __syncthreads();
  int idx = blockIdx.x * 1024 + threadIdx.x;
  if (idx < NNODES) head[idx] += off_s;
}

__global__ void scatter_kernel(const int* __restrict__ ei, int* __restrict__ head,
                               int2* __restrict__ spair){
  int idx = blockIdx.x * 256 + threadIdx.x;
  if (idx < NEDGES){
    int r = ei[idx], c = ei[NEDGES + idx];
    int p = atomicAdd(&head[r], 1);
    spair[p] = make_int2(r, c);
  }
}

// ---------------- edge kernel ----------------------------------------------
// 64 edges/block (sorted by row), 4 waves; wave owns 32 of 128 output cols.
// Column map: col = nb + 2*ln + nt  -> packed bf16x2 epilogue stores.
__global__ __launch_bounds__(256, 4) void edge_kernel(
    const ushort_t* __restrict__ hb, const float* __restrict__ pos,
    const int2* __restrict__ spair,
    const float* __restrict__ eW1, const float* __restrict__ eb1,
    const float* __restrict__ eb2, const float* __restrict__ cb1,
    const float* __restrict__ cW2,
    const ushort_t* __restrict__ eW1t, const ushort_t* __restrict__ eW2t,
    const ushort_t* __restrict__ cW1t,
    float* __restrict__ m_i, float* __restrict__ pos_sum)
{
  __shared__ __align__(16) ushort_t buf[TILE * 136];   // t1, then m_ij
  __shared__ int   row_l[TILE];
  __shared__ float sq_l[TILE];
  __shared__ float dx_l[TILE], dy_l[TILE], dz_l[TILE], w_l[TILE];

  const int t = threadIdx.x;
  const int base = blockIdx.x * TILE;
  const int lane = t & 63, q = lane >> 4, ln = lane & 15;
  const int nb = (t >> 6) * 32;
  const int c0 = nb + 2 * ln;                          // this lane's column pair

  // per-lane A-source rows (registers, no LDS dependency)
  int rs[4], cs[4];
  #pragma unroll
  for (int mt = 0; mt < 4; mt++){
    int2 rc = spair[base + mt*16 + ln];
    rs[mt] = rc.x; cs[mt] = rc.y;
  }

  // geometry staging (consumed after sync1)
  if (t < TILE){
    int2 rc = spair[base + t];
    row_l[t] = rc.x;
    float ax = pos[rc.x*3+0] - pos[rc.y*3+0];
    float ay = pos[rc.x*3+1] - pos[rc.y*3+1];
    float az = pos[rc.x*3+2] - pos[rc.y*3+2];
    dx_l[t] = ax; dy_l[t] = ay; dz_l[t] = az;
    sq_l[t] = ax*ax + ay*ay + az*az;
    w_l[t]  = 0.f;
  }

  floatx4 acc[4][2];
  #pragma unroll
  for (int mt = 0; mt < 4; mt++)
    #pragma unroll
    for (int nt = 0; nt < 2; nt++) acc[mt][nt] = (floatx4)0.f;

  // ---- GEMM1: [64 x 256] @ eW1t, A direct from global bf16 (no LDS use)
  #pragma unroll
  for (int ks = 0; ks < 8; ks++){
    const int sl = (ks & 3) * 32 + q * 8;
    short8 a[4], b[2];
    #pragma unroll
    for (int mt = 0; mt < 4; mt++){
      int src = (ks < 4) ? rs[mt] : cs[mt];
      a[mt] = *(const short8*)(hb + (size_t)src * H + sl);
    }
    #pragma unroll
    for (int nt = 0; nt < 2; nt++)
      b[nt] = *(const short8*)(eW1t + (size_t)(c0 + nt) * 256 + ks*32 + q*8);
    #pragma unroll
    for (int mt = 0; mt < 4; mt++)
      #pragma unroll
      for (int nt = 0; nt < 2; nt++)
        acc[mt][nt] = __builtin_amdgcn_mfma_f32_16x16x32_bf16(a[mt], b[nt], acc[mt][nt], 0, 0, 0);
  }
  __syncthreads();                                  // sync1: staging visible
  {
    float2 w256 = *(const float2*)(eW1 + 256 * H + c0);
    float2 e1   = *(const float2*)(eb1 + c0);
    #pragma unroll
    for (int mt = 0; mt < 4; mt++)
      #pragma unroll
      for (int r = 0; r < 4; r++){
        int m = mt*16 + q*4 + r;
        float sq = sq_l[m];
        float f0 = acc[mt][0][r] + sq * w256.x + e1.x;
        float f1 = acc[mt][1][r] + sq * w256.y + e1.y;
        *(uint32_t*)(buf + m * 136 + c0) = pk2bf(silu_f(f0), silu_f(f1));
      }
  }
  __syncthreads();                                  // sync2: t1 ready

  // ---- GEMM2: t1 @ eW2t -> m_ij
  #pragma unroll
  for (int mt = 0; mt < 4; mt++)
    #pragma unroll
    for (int nt = 0; nt < 2; nt++) acc[mt][nt] = (floatx4)0.f;
  #pragma unroll
  for (int ks = 0; ks < 4; ks++){
    short8 a[4], b[2];
    #pragma unroll
    for (int mt = 0; mt < 4; mt++)
      a[mt] = *(const short8*)(buf + (mt*16 + ln) * 136 + ks*32 + q*8);
    #pragma unroll
    for (int nt = 0; nt < 2; nt++)
      b[nt] = *(const short8*)(eW2t + (size_t)(c0 + nt) * 128 + ks*32 + q*8);
    #pragma unroll
    for (int mt = 0; mt < 4; mt++)
      #pragma unroll
      for (int nt = 0; nt < 2; nt++)
        acc[mt][nt] = __builtin_amdgcn_mfma_f32_16x16x32_bf16(a[mt], b[nt], acc[mt][nt], 0, 0, 0);
  }
  __syncthreads();                                  // sync3: all t1 reads done
  {
    float2 e2 = *(const float2*)(eb2 + c0);
    #pragma unroll
    for (int mt = 0; mt < 4; mt++)
      #pragma unroll
      for (int r = 0; r < 4; r++){
        int m = mt*16 + q*4 + r;
        float f0 = silu_f(acc[mt][0][r] + e2.x);
        float f1 = silu_f(acc[mt][1][r] + e2.y);
        *(uint32_t*)(buf + m * 136 + c0) = pk2bf(f0, f1);
      }
  }
  __syncthreads();                                  // sync4: m_ij ready

  // ---- GEMM3: m_ij @ cW1t ; dot with cW2 -> per-edge scalar weight
  #pragma unroll
  for (int mt = 0; mt < 4; mt++)
    #pragma unroll
    for (int nt = 0; nt < 2; nt++) acc[mt][nt] = (floatx4)0.f;
  #pragma unroll
  for (int ks = 0; ks < 4; ks++){
    short8 a[4], b[2];
    #pragma unroll
    for (int mt = 0; mt < 4; mt++)
      a[mt] = *(const short8*)(buf + (mt*16 + ln) * 136 + ks*32 + q*8);
    #pragma unroll
    for (int nt = 0; nt < 2; nt++)
      b[nt] = *(const short8*)(cW1t + (size_t)(c0 + nt) * 128 + ks*32 + q*8);
    #pragma unroll
    for (int mt = 0; mt < 4; mt++)
      #pragma unroll
      for (int nt = 0; nt < 2; nt++)
        acc[mt][nt] = __builtin_amdgcn_mfma_f32_16x16x32_bf16(a[mt], b[nt], acc[mt][nt], 0, 0, 0);
  }
  {
    float2 c1 = *(const float2*)(cb1 + c0);
    float2 c2 = *(const float2*)(cW2 + c0);
    #pragma unroll
    for (int mt = 0; mt < 4; mt++)
      #pragma unroll
      for (int r = 0; r < 4; r++){
        float p = silu_f(acc[mt][0][r] + c1.x) * c2.x
                + silu_f(acc[mt][1][r] + c1.y) * c2.y;
        p += __shfl_xor(p, 1);
        p += __shfl_xor(p, 2);
        p += __shfl_xor(p, 4);
        p += __shfl_xor(p, 8);
        if (ln == 0) atomicAdd(&w_l[mt*16 + q*4 + r], p);
      }
  }
  __syncthreads();                                  // sync5: w_l ready, buf=m_ij

  // ---- segmented reduce m_ij -> m_i; 4 groups x 16 edges x 64 col-pairs
  {
    int cp = (t & 63) * 2;
    int ms = (t >> 6) * 16;
    float a0 = 0.f, a1 = 0.f;
    int cur = row_l[ms];
    #pragma unroll 4
    for (int mm = 0; mm < 16; mm++){
      int m = ms + mm;
      int rr = row_l[m];
      uint32_t v = *(const uint32_t*)(buf + m * 136 + cp);
      if (rr != cur){
        unsafeAtomicAdd(&m_i[(size_t)cur * H + cp],     a0);
        unsafeAtomicAdd(&m_i[(size_t)cur * H + cp + 1], a1);
        a0 = 0.f; a1 = 0.f; cur = rr;
      }
      a0 += bf2f((ushort_t)(v & 0xffffu));
      a1 += bf2f((ushort_t)(v >> 16));
    }
    unsafeAtomicAdd(&m_i[(size_t)cur * H + cp],     a0);
    unsafeAtomicAdd(&m_i[(size_t)cur * H + cp + 1], a1);
  }
  // ---- pos segmented reduce with inline scaling (3 threads)
  if (t < 3){
    const float* src = (t == 0) ? dx_l : (t == 1) ? dy_l : dz_l;
    float accv = 0.f;
    int cur = row_l[0];
    for (int m = 0; m < TILE; m++){
      int rr = row_l[m];
      if (rr != cur){
        unsafeAtomicAdd(&pos_sum[cur*3 + t], accv);
        accv = 0.f; cur = rr;
      }
      float s = __builtin_amdgcn_rsqf(sq_l[m] + 1e-8f) * w_l[m];
      accv += src[m] * s;
    }
    unsafeAtomicAdd(&pos_sum[cur*3 + t], accv);
  }
}

// ---------------- node kernel ----------------------------------------------
__global__ __launch_bounds__(256, 3) void node_kernel(
    const float* __restrict__ h, const ushort_t* __restrict__ hb,
    const float* __restrict__ pos,
    const float* __restrict__ nb1, const float* __restrict__ nb2,
    const ushort_t* __restrict__ nW1t, const ushort_t* __restrict__ nW2t,
    const float* __restrict__ m_i, const float* __restrict__ pos_sum,
    const int* __restrict__ hist,
    float* __restrict__ h_out, float* __restrict__ pos_out)
{
  __shared__ __align__(16) ushort_t bufA[TILE * 264];
  __shared__ __align__(16) ushort_t bufT[TILE * 136];
  const int t = threadIdx.x;
  const int base = blockIdx.x * TILE;

  if (t < TILE){
    int node = base + t;
    if (node < NNODES){
      float c = fmaxf((float)hist[node], 1.f);
      float invc = __builtin_amdgcn_rcpf(c);
      pos_out[node*3+0] = pos[node*3+0] + pos_sum[node*3+0] * invc;
      pos_out[node*3+1] = pos[node*3+1] + pos_sum[node*3+1] * invc;
      pos_out[node*3+2] = pos[node*3+2] + pos_sum[node*3+2] * invc;
    }
  }
  { // gather [h(bf16 copy) | m_i(packed cvt)] -> bufA
    const int i = t >> 2, p = t & 3;
    const int node = base + i;
    ushort_t* dst = bufA + i * 264 + p * 64;
    if (node < NNODES){
      if (p < 2){
        const short8* sp = (const short8*)(hb + (size_t)node * H + p * 64);
        #pragma unroll
        for (int j = 0; j < 8; j++) ((short8*)dst)[j] = sp[j];
      } else {
        const float4* sp = (const float4*)(m_i + (size_t)node * H + (p - 2) * 64);
        #pragma unroll
        for (int j = 0; j < 8; j++){
          float4 v0 = sp[j*2], v1 = sp[j*2+1];
          uint4 uu;
          uu.x = pk2bf(v0.x, v0.y); uu.y = pk2bf(v0.z, v0.w);
          uu.z = pk2bf(v1.x, v1.y); uu.w = pk2bf(v1.z, v1.w);
          *(uint4*)(dst + j*8) = uu;
        }
      }
    } else {
      #pragma unroll
      for (int j = 0; j < 8; j++) ((short8*)dst)[j] = (short8)0;
    }
  }
  __syncthreads();

  const int lane = t & 63, q = lane >> 4, ln = lane & 15;
  const int nb_ = (t >> 6) * 32;
  const int c0 = nb_ + 2 * ln;

  floatx4 acc[4][2];
  #pragma unroll
  for (int mt = 0; mt < 4; mt++)
    #pragma unroll
    for (int nt = 0; nt < 2; nt++) acc[mt][nt] = (floatx4)0.f;
  #pragma unroll
  for (int ks = 0; ks < 8; ks++){
    short8 a[4], b[2];
    #pragma unroll
    for (int mt = 0; mt < 4; mt++)
      a[mt] = *(const short8*)(bufA + (mt*16 + ln) * 264 + ks*32 + q*8);
    #pragma unroll
    for (int nt = 0; nt < 2; nt++)
      b[nt] = *(const short8*)(nW1t + (size_t)(c0 + nt) * 256 + ks*32 + q*8);
    #pragma unroll
    for (int mt = 0; mt < 4; mt++)
      #pragma unroll
      for (int nt = 0; nt < 2; nt++)
        acc[mt][nt] = __builtin_amdgcn_mfma_f32_16x16x32_bf16(a[mt], b[nt], acc[mt][nt], 0, 0, 0);
  }
  {
    float2 b1 = *(const float2*)(nb1 + c0);
    #pragma unroll
    for (int mt = 0; mt < 4; mt++)
      #pragma unroll
      for (int r = 0; r < 4; r++){
        int m = mt*16 + q*4 + r;
        float f0 = silu_f(acc[mt][0][r] + b1.x);
        float f1 = silu_f(acc[mt][1][r] + b1.y);
        *(uint32_t*)(bufT + m * 136 + c0) = pk2bf(f0, f1);
      }
  }
  __syncthreads();

  #pragma unroll
  for (int mt = 0; mt < 4; mt++)
    #pragma unroll
    for (int nt = 0; nt < 2; nt++) acc[mt][nt] = (floatx4)0.f;
  #pragma unroll
  for (int ks = 0; ks < 4; ks++){
    short8 a[4], b[2];
    #pragma unroll
    for (int mt = 0; mt < 4; mt++)
      a[mt] = *(const short8*)(bufT + (mt*16 + ln) * 136 + ks*32 + q*8);
    #pragma unroll
    for (int nt = 0; nt < 2; nt++)
      b[nt] = *(const short8*)(nW2t + (size_t)(c0 + nt) * 128 + ks*32 + q*8);
    #pragma unroll
    for (int mt = 0; mt < 4; mt++)
      #pragma unroll
      for (int nt = 0; nt < 2; nt++)
        acc[mt][nt] = __builtin_amdgcn_mfma_f32_16x16x32_bf16(a[mt], b[nt], acc[mt][nt], 0, 0, 0);
  }
  {
    float2 b2 = *(const float2*)(nb2 + c0);
    #pragma unroll
    for (int mt = 0; mt < 4; mt++)
      #pragma unroll
      for (int r = 0; r < 4; r++){
        int m = mt*16 + q*4 + r;
        int node = base + m;
        if (node < NNODES){
          const float2 hv = *(const float2*)(h + (size_t)node * H + c0);
          float2 o;
          o.x = hv.x + acc[mt][0][r] + b2.x;
          o.y = hv.y + acc[mt][1][r] + b2.y;
          *(float2*)(h_out + (size_t)node * H + c0) = o;
        }
      }
  }
}

// ---------------- launch ----------------------------------------------------
extern "C" void kernel_launch(void* const* d_in, const int* in_sizes, int n_in,
                              void* d_out, int out_size, void* d_ws, size_t ws_size,
                              hipStream_t stream){
  const float* h   = (const float*)d_in[0];
  const float* pos = (const float*)d_in[1];
  const int*   ei  = (const int*)d_in[2];
  const float* eW1 = (const float*)d_in[3];
  const float* eb1 = (const float*)d_in[4];
  const float* eW2 = (const float*)d_in[5];
  const float* eb2 = (const float*)d_in[6];
  const float* cW1 = (const float*)d_in[7];
  const float* cb1 = (const float*)d_in[8];
  const float* cW2 = (const float*)d_in[9];
  const float* nW1 = (const float*)d_in[10];
  const float* nb1 = (const float*)d_in[11];
  const float* nW2 = (const float*)d_in[12];
  const float* nb2 = (const float*)d_in[13];

  char* ws = (char*)d_ws;
  float*    m_i     = (float*)   (ws);                 // 10,240,000 B
  float*    pos_sum = (float*)   (ws + 10240000);      //    240,000 B
  int*      hist    = (int*)     (ws + 10480000);      //     80,000 B
  int*      head    = (int*)     (ws + 10560000);      //     80,000 B
  int*      totals  = (int*)     (ws + 10640000);      //      2,048 B
  int2*     spair   = (int2*)    (ws + 10644096);      //  5,120,000 B
  ushort_t* h_bf    = (ushort_t*)(ws + 15764096);      //  5,120,000 B
  ushort_t* eW1t    = (ushort_t*)(ws + 20884096);      //     65,536 B
  ushort_t* eW2t    = (ushort_t*)(ws + 20949632);      //     32,768 B
  ushort_t* cW1t    = (ushort_t*)(ws + 20982400);      //     32,768 B
  ushort_t* nW1t    = (ushort_t*)(ws + 21015168);      //     65,536 B
  ushort_t* nW2t    = (ushort_t*)(ws + 21080704);      //     32,768 B

  (void)hipMemsetAsync(hist, 0, 80000, stream);        // hist only; m_i/pos_sum zeroed in setup

  setup_kernel<<<6757, 256, 0, stream>>>(eW1, eW2, cW1, nW1, nW2, h, ei,
                                         eW1t, eW2t, cW1t, nW1t, nW2t, h_bf, hist,
                                         (float4*)ws);
  scanA_kernel<<<SCAN_BLOCKS, 1024, 0, stream>>>(hist, head, totals);
  scanC_kernel<<<SCAN_BLOCKS, 1024, 0, stream>>>(totals, head);
  scatter_kernel<<<(NEDGES + 255) / 256, 256, 0, stream>>>(ei, head, spair);

  edge_kernel<<<NEDGES / TILE, 256, 0, stream>>>(h_bf, pos, spair,
                                                 eW1, eb1, eb2, cb1, cW2,
                                                 eW1t, eW2t, cW1t, m_i, pos_sum);

  float* h_out   = (float*)d_out;
  float* pos_out = h_out + (size_t)NNODES * H;
  node_kernel<<<(NNODES + TILE - 1) / TILE, 256, 0, stream>>>(h, h_bf, pos, nb1, nb2,
                                                              nW1t, nW2t, m_i, pos_sum,
                                                              hist, h_out, pos_out);
}

// Round 8
// 404.646 us; speedup vs baseline: 2.2651x; 1.1300x over previous
//
#include <hip/hip_runtime.h>
#include <hip/hip_bf16.h>
#include <cstdint>

#define H 128
#define NNODES 20000
#define NEDGES 640000
#define TILE 64
#define SCAN_BLOCKS 20

typedef unsigned short ushort_t;
typedef __attribute__((ext_vector_type(8))) short short8;
typedef __attribute__((ext_vector_type(4))) float floatx4;

__device__ __forceinline__ ushort_t f2bf(float f){
  uint32_t u = __builtin_bit_cast(uint32_t, f);
  u += 0x7fffu + ((u >> 16) & 1u);           // RNE
  return (ushort_t)(u >> 16);
}
__device__ __forceinline__ float bf2f(ushort_t s){
  uint32_t u = ((uint32_t)s) << 16;
  return __builtin_bit_cast(float, u);
}
// packed RNE fp32x2 -> bf16x2 (v_cvt_pk_bf16_f32 on gfx950)
__device__ __forceinline__ uint32_t pk2bf(float lo, float hi){
  __hip_bfloat162 h2 = __float22bfloat162_rn(make_float2(lo, hi));
  uint32_t u;
  __builtin_memcpy(&u, &h2, 4);
  return u;
}
// unpack bf16x2 dword -> two floats
__device__ __forceinline__ float2 bfpair(uint32_t u){
  float2 r;
  uint32_t lo = u << 16, hi = u & 0xffff0000u;
  r.x = __builtin_bit_cast(float, lo);
  r.y = __builtin_bit_cast(float, hi);
  return r;
}
// fast silu: v_exp_f32 + v_rcp_f32
__device__ __forceinline__ float silu_f(float x){
  float e = __builtin_amdgcn_exp2f(-1.44269504089f * x);
  return x * __builtin_amdgcn_rcpf(1.f + e);
}

// ---- setup: weight transpose+cvt, degree histogram, zero m_i/pos_sum -------
__global__ void setup_kernel(const float* __restrict__ eW1, const float* __restrict__ eW2,
                             const float* __restrict__ cW1, const float* __restrict__ nW1,
                             const float* __restrict__ nW2, const int* __restrict__ ei,
                             ushort_t* __restrict__ eW1t, ushort_t* __restrict__ eW2t,
                             ushort_t* __restrict__ cW1t, ushort_t* __restrict__ nW1t,
                             ushort_t* __restrict__ nW2t,
                             int* __restrict__ hist, float4* __restrict__ zbase){
  int idx = blockIdx.x * 256 + threadIdx.x;
  if (idx < 32768){                      // eW1t[n*256+k] = eW1[k*128+n], k<256
    int n = idx >> 8, k = idx & 255;
    eW1t[idx] = f2bf(eW1[k * H + n]);
  } else if (idx < 49152){
    int j = idx - 32768; int n = j >> 7, k = j & 127;
    eW2t[j] = f2bf(eW2[k * H + n]);
  } else if (idx < 65536){
    int j = idx - 49152; int n = j >> 7, k = j & 127;
    cW1t[j] = f2bf(cW1[k * H + n]);
  } else if (idx < 98304){
    int j = idx - 65536; int n = j >> 8, k = j & 255;
    nW1t[j] = f2bf(nW1[k * H + n]);
  } else if (idx < 114688){
    int j = idx - 98304; int n = j >> 7, k = j & 127;
    nW2t[j] = f2bf(nW2[k * H + n]);
  } else if (idx < 754688){              // degree histogram
    int j = idx - 114688;
    atomicAdd(&hist[ei[j]], 1);
  } else {                               // zero m_i + pos_sum (655000 float4s)
    int j = idx - 754688;
    if (j < 655000) zbase[j] = make_float4(0.f, 0.f, 0.f, 0.f);
  }
}

// ---- P/Q precompute: P = h @ eW1[0:128], Q = h @ eW1[128:256], bf16 out ----
__global__ void pq_kernel(const float* __restrict__ h, const ushort_t* __restrict__ eW1t,
                          ushort_t* __restrict__ Pb, ushort_t* __restrict__ Qb){
  const int t = threadIdx.x;
  const int lane = t & 63, q = lane >> 4, ln = lane & 15;
  const int nb = (t >> 6) * 32;
  const int c0 = nb + 2 * ln;
  const int base = blockIdx.x * 64;

  floatx4 accP[4][2], accQ[4][2];
  #pragma unroll
  for (int mt = 0; mt < 4; mt++)
    #pragma unroll
    for (int nt = 0; nt < 2; nt++){ accP[mt][nt] = (floatx4)0.f; accQ[mt][nt] = (floatx4)0.f; }

  #pragma unroll
  for (int ks = 0; ks < 4; ks++){
    short8 a[4];
    #pragma unroll
    for (int mt = 0; mt < 4; mt++){
      int node = base + mt*16 + ln;
      if (node >= NNODES) node = NNODES - 1;
      const float* hp = h + (size_t)node * H + ks*32 + q*8;
      float4 v0 = *(const float4*)hp;
      float4 v1 = *(const float4*)(hp + 4);
      uint32_t tw[4];
      tw[0] = pk2bf(v0.x, v0.y); tw[1] = pk2bf(v0.z, v0.w);
      tw[2] = pk2bf(v1.x, v1.y); tw[3] = pk2bf(v1.z, v1.w);
      __builtin_memcpy(&a[mt], tw, 16);
    }
    short8 bP[2], bQ[2];
    #pragma unroll
    for (int nt = 0; nt < 2; nt++){
      bP[nt] = *(const short8*)(eW1t + (size_t)(c0 + nt) * 256 + ks*32 + q*8);
      bQ[nt] = *(const short8*)(eW1t + (size_t)(c0 + nt) * 256 + 128 + ks*32 + q*8);
    }
    #pragma unroll
    for (int mt = 0; mt < 4; mt++)
      #pragma unroll
      for (int nt = 0; nt < 2; nt++){
        accP[mt][nt] = __builtin_amdgcn_mfma_f32_16x16x32_bf16(a[mt], bP[nt], accP[mt][nt], 0, 0, 0);
        accQ[mt][nt] = __builtin_amdgcn_mfma_f32_16x16x32_bf16(a[mt], bQ[nt], accQ[mt][nt], 0, 0, 0);
      }
  }
  #pragma unroll
  for (int mt = 0; mt < 4; mt++)
    #pragma unroll
    for (int r = 0; r < 4; r++){
      int node = base + mt*16 + q*4 + r;
      if (node < NNODES){
        *(uint32_t*)(Pb + (size_t)node * H + c0) = pk2bf(accP[mt][0][r], accP[mt][1][r]);
        *(uint32_t*)(Qb + (size_t)node * H + c0) = pk2bf(accQ[mt][0][r], accQ[mt][1][r]);
      }
    }
}

// ---------------- CSR build ------------------------------------------------
__global__ void scanA_kernel(const int* __restrict__ hist, int* __restrict__ head,
                             int* __restrict__ totals){
  __shared__ int s[1024];
  const int t = threadIdx.x;
  const int idx = blockIdx.x * 1024 + t;
  int v = (idx < NNODES) ? hist[idx] : 0;
  s[t] = v;
  __syncthreads();
  for (int off = 1; off < 1024; off <<= 1){
    int tmp = (t >= off) ? s[t - off] : 0;
    __syncthreads();
    s[t] += tmp;
    __syncthreads();
  }
  if (idx < NNODES) head[idx] = s[t] - v;          // exclusive within block
  if (t == 1023) totals[blockIdx.x] = s[t];
}

__global__ void scanC_kernel(const int* __restrict__ totals, int* __restrict__ head){
  __shared__ int off_s;
  if (threadIdx.x == 0){
    int a = 0;
    for (int i = 0; i < (int)blockIdx.x; i++) a += totals[i];
    off_s = a;
  }
  __syncthreads();
  int idx = blockIdx.x * 1024 + threadIdx.x;
  if (idx < NNODES) head[idx] += off_s;
}

__global__ void scatter_kernel(const int* __restrict__ ei, int* __restrict__ head,
                               int2* __restrict__ spair){
  int idx = blockIdx.x * 256 + threadIdx.x;
  if (idx < NEDGES){
    int r = ei[idx], c = ei[NEDGES + idx];
    int p = atomicAdd(&head[r], 1);
    spair[p] = make_int2(r, c);
  }
}

// ---------------- edge kernel ----------------------------------------------
// 64 edges/block (sorted by row), 4 waves; wave owns 32 of 128 output cols.
// GEMM1 eliminated: t1 = silu(P[row]+Q[col]+sq*w256+eb1) built by gather-add.
__global__ __launch_bounds__(256, 4) void edge_kernel(
    const ushort_t* __restrict__ Pb, const ushort_t* __restrict__ Qb,
    const float* __restrict__ pos, const int2* __restrict__ spair,
    const float* __restrict__ eW1, const float* __restrict__ eb1,
    const float* __restrict__ eb2, const float* __restrict__ cb1,
    const float* __restrict__ cW2,
    const ushort_t* __restrict__ eW2t, const ushort_t* __restrict__ cW1t,
    float* __restrict__ m_i, float* __restrict__ pos_sum)
{
  __shared__ __align__(16) ushort_t buf[TILE * 136];   // t1, then m_ij
  __shared__ int   row_l[TILE];
  __shared__ float sq_l[TILE];
  __shared__ float dx_l[TILE], dy_l[TILE], dz_l[TILE], w_l[TILE];

  const int t = threadIdx.x;
  const int base = blockIdx.x * TILE;
  const int lane = t & 63, q = lane >> 4, ln = lane & 15;
  const int nb = (t >> 6) * 32;
  const int c0 = nb + 2 * ln;                          // this lane's column pair

  // geometry staging (consumed after sync4/5)
  if (t < TILE){
    int2 rc = spair[base + t];
    row_l[t] = rc.x;
    float ax = pos[rc.x*3+0] - pos[rc.y*3+0];
    float ay = pos[rc.x*3+1] - pos[rc.y*3+1];
    float az = pos[rc.x*3+2] - pos[rc.y*3+2];
    dx_l[t] = ax; dy_l[t] = ay; dz_l[t] = az;
    sq_l[t] = ax*ax + ay*ay + az*az;
    w_l[t]  = 0.f;
  }

  // ---- t1 build: thread (i,p) handles 32 cols of edge i
  {
    const int i = t >> 2, p = t & 3;
    int2 rc = spair[base + i];
    float ax = pos[rc.x*3+0] - pos[rc.y*3+0];
    float ay = pos[rc.x*3+1] - pos[rc.y*3+1];
    float az = pos[rc.x*3+2] - pos[rc.y*3+2];
    float sq = ax*ax + ay*ay + az*az;
    const uint4*  Pp = (const uint4*)(Pb + (size_t)rc.x * H + p*32);
    const uint4*  Qp = (const uint4*)(Qb + (size_t)rc.y * H + p*32);
    const float4* wp = (const float4*)(eW1 + 256 * H + p*32);
    const float4* ep = (const float4*)(eb1 + p*32);
    ushort_t* dst = buf + i * 136 + p*32;
    #pragma unroll
    for (int j = 0; j < 4; j++){
      uint4 pv = Pp[j], qv = Qp[j];
      float4 w0 = wp[2*j], w1 = wp[2*j+1];
      float4 e0 = ep[2*j], e1 = ep[2*j+1];
      float2 p0 = bfpair(pv.x), p1 = bfpair(pv.y), p2 = bfpair(pv.z), p3 = bfpair(pv.w);
      float2 q0 = bfpair(qv.x), q1 = bfpair(qv.y), q2 = bfpair(qv.z), q3 = bfpair(qv.w);
      float f0 = p0.x + q0.x + sq * w0.x + e0.x;
      float f1 = p0.y + q0.y + sq * w0.y + e0.y;
      float f2 = p1.x + q1.x + sq * w0.z + e0.z;
      float f3 = p1.y + q1.y + sq * w0.w + e0.w;
      float f4 = p2.x + q2.x + sq * w1.x + e1.x;
      float f5 = p2.y + q2.y + sq * w1.y + e1.y;
      float f6 = p3.x + q3.x + sq * w1.z + e1.z;
      float f7 = p3.y + q3.y + sq * w1.w + e1.w;
      uint4 out;
      out.x = pk2bf(silu_f(f0), silu_f(f1));
      out.y = pk2bf(silu_f(f2), silu_f(f3));
      out.z = pk2bf(silu_f(f4), silu_f(f5));
      out.w = pk2bf(silu_f(f6), silu_f(f7));
      *(uint4*)(dst + j*8) = out;
    }
  }
  __syncthreads();                                  // sync2: t1 + staging ready

  floatx4 acc[4][2];

  // ---- GEMM2: t1 @ eW2t -> m_ij
  #pragma unroll
  for (int mt = 0; mt < 4; mt++)
    #pragma unroll
    for (int nt = 0; nt < 2; nt++) acc[mt][nt] = (floatx4)0.f;
  #pragma unroll
  for (int ks = 0; ks < 4; ks++){
    short8 a[4], b[2];
    #pragma unroll
    for (int mt = 0; mt < 4; mt++)
      a[mt] = *(const short8*)(buf + (mt*16 + ln) * 136 + ks*32 + q*8);
    #pragma unroll
    for (int nt = 0; nt < 2; nt++)
      b[nt] = *(const short8*)(eW2t + (size_t)(c0 + nt) * 128 + ks*32 + q*8);
    #pragma unroll
    for (int mt = 0; mt < 4; mt++)
      #pragma unroll
      for (int nt = 0; nt < 2; nt++)
        acc[mt][nt] = __builtin_amdgcn_mfma_f32_16x16x32_bf16(a[mt], b[nt], acc[mt][nt], 0, 0, 0);
  }
  __syncthreads();                                  // sync3: all t1 reads done
  {
    float2 e2 = *(const float2*)(eb2 + c0);
    #pragma unroll
    for (int mt = 0; mt < 4; mt++)
      #pragma unroll
      for (int r = 0; r < 4; r++){
        int m = mt*16 + q*4 + r;
        float f0 = silu_f(acc[mt][0][r] + e2.x);
        float f1 = silu_f(acc[mt][1][r] + e2.y);
        *(uint32_t*)(buf + m * 136 + c0) = pk2bf(f0, f1);
      }
  }
  __syncthreads();                                  // sync4: m_ij ready

  // ---- GEMM3: m_ij @ cW1t ; dot with cW2 -> per-edge scalar weight
  #pragma unroll
  for (int mt = 0; mt < 4; mt++)
    #pragma unroll
    for (int nt = 0; nt < 2; nt++) acc[mt][nt] = (floatx4)0.f;
  #pragma unroll
  for (int ks = 0; ks < 4; ks++){
    short8 a[4], b[2];
    #pragma unroll
    for (int mt = 0; mt < 4; mt++)
      a[mt] = *(const short8*)(buf + (mt*16 + ln) * 136 + ks*32 + q*8);
    #pragma unroll
    for (int nt = 0; nt < 2; nt++)
      b[nt] = *(const short8*)(cW1t + (size_t)(c0 + nt) * 128 + ks*32 + q*8);
    #pragma unroll
    for (int mt = 0; mt < 4; mt++)
      #pragma unroll
      for (int nt = 0; nt < 2; nt++)
        acc[mt][nt] = __builtin_amdgcn_mfma_f32_16x16x32_bf16(a[mt], b[nt], acc[mt][nt], 0, 0, 0);
  }
  {
    float2 c1 = *(const float2*)(cb1 + c0);
    float2 c2 = *(const float2*)(cW2 + c0);
    #pragma unroll
    for (int mt = 0; mt < 4; mt++)
      #pragma unroll
      for (int r = 0; r < 4; r++){
        float p = silu_f(acc[mt][0][r] + c1.x) * c2.x
                + silu_f(acc[mt][1][r] + c1.y) * c2.y;
        p += __shfl_xor(p, 1);
        p += __shfl_xor(p, 2);
        p += __shfl_xor(p, 4);
        p += __shfl_xor(p, 8);
        if (ln == 0) atomicAdd(&w_l[mt*16 + q*4 + r], p);
      }
  }
  __syncthreads();                                  // sync5: w_l ready, buf=m_ij

  // ---- segmented reduce m_ij -> m_i; 2 groups x 32 edges x 128 cols
  {
    int col = t & 127;
    int ms  = (t >> 7) * 32;
    float a0 = 0.f;
    int cur = row_l[ms];
    #pragma unroll 4
    for (int mm = 0; mm < 32; mm++){
      int m = ms + mm;
      int rr = row_l[m];
      float v = bf2f(buf[m * 136 + col]);
      if (rr != cur){
        unsafeAtomicAdd(&m_i[(size_t)cur * H + col], a0);
        a0 = 0.f; cur = rr;
      }
      a0 += v;
    }
    unsafeAtomicAdd(&m_i[(size_t)cur * H + col], a0);
  }
  // ---- pos segmented reduce with inline scaling (3 threads)
  if (t < 3){
    const float* src = (t == 0) ? dx_l : (t == 1) ? dy_l : dz_l;
    float accv = 0.f;
    int cur = row_l[0];
    for (int m = 0; m < TILE; m++){
      int rr = row_l[m];
      if (rr != cur){
        unsafeAtomicAdd(&pos_sum[cur*3 + t], accv);
        accv = 0.f; cur = rr;
      }
      float s = __builtin_amdgcn_rsqf(sq_l[m] + 1e-8f) * w_l[m];
      accv += src[m] * s;
    }
    unsafeAtomicAdd(&pos_sum[cur*3 + t], accv);
  }
}

// ---------------- node kernel ----------------------------------------------
__global__ __launch_bounds__(256, 3) void node_kernel(
    const float* __restrict__ h, const float* __restrict__ pos,
    const float* __restrict__ nb1, const float* __restrict__ nb2,
    const ushort_t* __restrict__ nW1t, const ushort_t* __restrict__ nW2t,
    const float* __restrict__ m_i, const float* __restrict__ pos_sum,
    const int* __restrict__ hist,
    float* __restrict__ h_out, float* __restrict__ pos_out)
{
  __shared__ __align__(16) ushort_t bufA[TILE * 264];
  __shared__ __align__(16) ushort_t bufT[TILE * 136];
  const int t = threadIdx.x;
  const int base = blockIdx.x * TILE;

  if (t < TILE){
    int node = base + t;
    if (node < NNODES){
      float c = fmaxf((float)hist[node], 1.f);
      float invc = __builtin_amdgcn_rcpf(c);
      pos_out[node*3+0] = pos[node*3+0] + pos_sum[node*3+0] * invc;
      pos_out[node*3+1] = pos[node*3+1] + pos_sum[node*3+1] * invc;
      pos_out[node*3+2] = pos[node*3+2] + pos_sum[node*3+2] * invc;
    }
  }
  { // gather [h | m_i] (fp32 -> packed bf16) -> bufA
    const int i = t >> 2, p = t & 3;
    const int node = base + i;
    ushort_t* dst = bufA + i * 264 + p * 64;
    if (node < NNODES){
      const float* s = (p < 2) ? (h + (size_t)node * H + p * 64)
                               : (m_i + (size_t)node * H + (p - 2) * 64);
      const float4* sp = (const float4*)s;
      #pragma unroll
      for (int j = 0; j < 8; j++){
        float4 v0 = sp[j*2], v1 = sp[j*2+1];
        uint4 uu;
        uu.x = pk2bf(v0.x, v0.y); uu.y = pk2bf(v0.z, v0.w);
        uu.z = pk2bf(v1.x, v1.y); uu.w = pk2bf(v1.z, v1.w);
        *(uint4*)(dst + j*8) = uu;
      }
    } else {
      #pragma unroll
      for (int j = 0; j < 8; j++) ((short8*)dst)[j] = (short8)0;
    }
  }
  __syncthreads();

  const int lane = t & 63, q = lane >> 4, ln = lane & 15;
  const int nb_ = (t >> 6) * 32;
  const int c0 = nb_ + 2 * ln;

  floatx4 acc[4][2];
  #pragma unroll
  for (int mt = 0; mt < 4; mt++)
    #pragma unroll
    for (int nt = 0; nt < 2; nt++) acc[mt][nt] = (floatx4)0.f;
  #pragma unroll
  for (int ks = 0; ks < 8; ks++){
    short8 a[4], b[2];
    #pragma unroll
    for (int mt = 0; mt < 4; mt++)
      a[mt] = *(const short8*)(bufA + (mt*16 + ln) * 264 + ks*32 + q*8);
    #pragma unroll
    for (int nt = 0; nt < 2; nt++)
      b[nt] = *(const short8*)(nW1t + (size_t)(c0 + nt) * 256 + ks*32 + q*8);
    #pragma unroll
    for (int mt = 0; mt < 4; mt++)
      #pragma unroll
      for (int nt = 0; nt < 2; nt++)
        acc[mt][nt] = __builtin_amdgcn_mfma_f32_16x16x32_bf16(a[mt], b[nt], acc[mt][nt], 0, 0, 0);
  }
  {
    float2 b1 = *(const float2*)(nb1 + c0);
    #pragma unroll
    for (int mt = 0; mt < 4; mt++)
      #pragma unroll
      for (int r = 0; r < 4; r++){
        int m = mt*16 + q*4 + r;
        float f0 = silu_f(acc[mt][0][r] + b1.x);
        float f1 = silu_f(acc[mt][1][r] + b1.y);
        *(uint32_t*)(bufT + m * 136 + c0) = pk2bf(f0, f1);
      }
  }
  __syncthreads();

  #pragma unroll
  for (int mt = 0; mt < 4; mt++)
    #pragma unroll
    for (int nt = 0; nt < 2; nt++) acc[mt][nt] = (floatx4)0.f;
  #pragma unroll
  for (int ks = 0; ks < 4; ks++){
    short8 a[4], b[2];
    #pragma unroll
    for (int mt = 0; mt < 4; mt++)
      a[mt] = *(const short8*)(bufT + (mt*16 + ln) * 136 + ks*32 + q*8);
    #pragma unroll
    for (int nt = 0; nt < 2; nt++)
      b[nt] = *(const short8*)(nW2t + (size_t)(c0 + nt) * 128 + ks*32 + q*8);
    #pragma unroll
    for (int mt = 0; mt < 4; mt++)
      #pragma unroll
      for (int nt = 0; nt < 2; nt++)
        acc[mt][nt] = __builtin_amdgcn_mfma_f32_16x16x32_bf16(a[mt], b[nt], acc[mt][nt], 0, 0, 0);
  }
  {
    float2 b2 = *(const float2*)(nb2 + c0);
    #pragma unroll
    for (int mt = 0; mt < 4; mt++)
      #pragma unroll
      for (int r = 0; r < 4; r++){
        int m = mt*16 + q*4 + r;
        int node = base + m;
        if (node < NNODES){
          const float2 hv = *(const float2*)(h + (size_t)node * H + c0);
          float2 o;
          o.x = hv.x + acc[mt][0][r] + b2.x;
          o.y = hv.y + acc[mt][1][r] + b2.y;
          *(float2*)(h_out + (size_t)node * H + c0) = o;
        }
      }
  }
}

// ---------------- launch ----------------------------------------------------
extern "C" void kernel_launch(void* const* d_in, const int* in_sizes, int n_in,
                              void* d_out, int out_size, void* d_ws, size_t ws_size,
                              hipStream_t stream){
  const float* h   = (const float*)d_in[0];
  const float* pos = (const float*)d_in[1];
  const int*   ei  = (const int*)d_in[2];
  const float* eW1 = (const float*)d_in[3];
  const float* eb1 = (const float*)d_in[4];
  const float* eW2 = (const float*)d_in[5];
  const float* eb2 = (const float*)d_in[6];
  const float* cW1 = (const float*)d_in[7];
  const float* cb1 = (const float*)d_in[8];
  const float* cW2 = (const float*)d_in[9];
  const float* nW1 = (const float*)d_in[10];
  const float* nb1 = (const float*)d_in[11];
  const float* nW2 = (const float*)d_in[12];
  const float* nb2 = (const float*)d_in[13];

  char* ws = (char*)d_ws;
  float*    m_i     = (float*)   (ws);                 // 10,240,000 B
  float*    pos_sum = (float*)   (ws + 10240000);      //    240,000 B
  int*      hist    = (int*)     (ws + 10480000);      //     80,000 B
  int*      head    = (int*)     (ws + 10560000);      //     80,000 B
  int*      totals  = (int*)     (ws + 10640000);      //      2,048 B
  int2*     spair   = (int2*)    (ws + 10644096);      //  5,120,000 B
  ushort_t* Pb      = (ushort_t*)(ws + 15764096);      //  5,120,000 B
  ushort_t* eW1t    = (ushort_t*)(ws + 20884096);      //     65,536 B
  ushort_t* eW2t    = (ushort_t*)(ws + 20949632);      //     32,768 B
  ushort_t* cW1t    = (ushort_t*)(ws + 20982400);      //     32,768 B
  ushort_t* nW1t    = (ushort_t*)(ws + 21015168);      //     65,536 B
  ushort_t* nW2t    = (ushort_t*)(ws + 21080704);      //     32,768 B
  ushort_t* Qb      = (ushort_t*)(ws + 21113472);      //  5,120,000 B  (end ~26.2 MB)

  (void)hipMemsetAsync(hist, 0, 80000, stream);        // hist only; m_i/pos_sum zeroed in setup

  // threads: 114688 (weights) + 640000 (hist) + 655000 (zero) = 1,409,688
  setup_kernel<<<5507, 256, 0, stream>>>(eW1, eW2, cW1, nW1, nW2, ei,
                                         eW1t, eW2t, cW1t, nW1t, nW2t, hist,
                                         (float4*)ws);
  pq_kernel<<<(NNODES + 63) / 64, 256, 0, stream>>>(h, eW1t, Pb, Qb);
  scanA_kernel<<<SCAN_BLOCKS, 1024, 0, stream>>>(hist, head, totals);
  scanC_kernel<<<SCAN_BLOCKS, 1024, 0, stream>>>(totals, head);
  scatter_kernel<<<(NEDGES + 255) / 256, 256, 0, stream>>>(ei, head, spair);

  edge_kernel<<<NEDGES / TILE, 256, 0, stream>>>(Pb, Qb, pos, spair,
                                                 eW1, eb1, eb2, cb1, cW2,
                                                 eW2t, cW1t, m_i, pos_sum);

  float* h_out   = (float*)d_out;
  float* pos_out = h_out + (size_t)NNODES * H;
  node_kernel<<<(NNODES + TILE - 1) / TILE, 256, 0, stream>>>(h, pos, nb1, nb2,
                                                              nW1t, nW2t, m_i, pos_sum,
                                                              hist, h_out, pos_out);
}